// Round 1
// 2481.862 us; speedup vs baseline: 1.0880x; 1.0880x over previous
//
#include <hip/hip_runtime.h>
#include <math.h>

#define T_TOK 32768
#define TKA   65536
#define DIM   1024
#define NE    16
#define IDIM  2816
#define CAP   5120

typedef short short8 __attribute__((ext_vector_type(8)));
typedef float floatx4 __attribute__((ext_vector_type(4)));

__device__ __forceinline__ unsigned short f2bf(float f) {
  unsigned int u = __float_as_uint(f);
  u = u + 0x7FFFu + ((u >> 16) & 1u);   // round-to-nearest-even
  return (unsigned short)(u >> 16);
}
__device__ __forceinline__ float bf2f(unsigned short h) {
  return __uint_as_float(((unsigned int)h) << 16);
}

// async global->LDS, 16B per lane. LDS dst must be the wave-uniform base;
// HW adds lane*16 (m104/m108 semantics).
__device__ __forceinline__ void gld_lds16(const void* g, void* l) {
  __builtin_amdgcn_global_load_lds(
      (const __attribute__((address_space(1))) unsigned int*)(unsigned long long)g,
      (__attribute__((address_space(3))) unsigned int*)(unsigned int)(unsigned long long)l,
      16, 0, 0);
}

// ---------------- pre-pass: conversions / transposes ----------------

__global__ void cvtx_kernel(const float* __restrict__ in, unsigned short* __restrict__ out) {
  size_t i = ((size_t)blockIdx.x * 256 + threadIdx.x) * 8;
  float4 a = *(const float4*)(in + i);
  float4 b = *(const float4*)(in + i + 4);
  short8 v;
  v[0] = (short)f2bf(a.x); v[1] = (short)f2bf(a.y); v[2] = (short)f2bf(a.z); v[3] = (short)f2bf(a.w);
  v[4] = (short)f2bf(b.x); v[5] = (short)f2bf(b.y); v[6] = (short)f2bf(b.z); v[7] = (short)f2bf(b.w);
  *(short8*)(out + i) = v;
}

// in: [e][R][Cin] fp32  ->  out: [e][Cin][R] bf16   (R, Cin multiples of 64)
__global__ void transpose_cvt(const float* __restrict__ in, unsigned short* __restrict__ out,
                              int R, int Cin) {
  int e = blockIdx.z;
  size_t base = (size_t)e * R * Cin;
  int ct = blockIdx.x;   // tile over input cols
  int rt = blockIdx.y;   // tile over input rows
  __shared__ unsigned short Ts[64][72];
  int tx = threadIdx.x & 63, ty = threadIdx.x >> 6;
#pragma unroll
  for (int j = 0; j < 16; j++) {
    int r = rt * 64 + ty + j * 4;
    int c = ct * 64 + tx;
    Ts[tx][ty + j * 4] = f2bf(in[base + (size_t)r * Cin + c]);
  }
  __syncthreads();
#pragma unroll
  for (int j = 0; j < 16; j++) {
    int cl = ty + j * 4;
    out[base + (size_t)(ct * 64 + cl) * R + rt * 64 + tx] = Ts[cl][tx];
  }
}

// ---------------- router / stats / capacity ----------------

__global__ void router_kernel(const float* __restrict__ x, const float* __restrict__ router,
                              float* __restrict__ logits) {
  int tid = blockIdx.x * 256 + threadIdx.x;   // 524288 = T*16 threads
  int tk = tid >> 4, e = tid & 15;
  const float* xr = x + (size_t)tk * DIM;
  float acc = 0.f;
#pragma unroll 8
  for (int d = 0; d < DIM; d++) acc = fmaf(xr[d], router[d * NE + e], acc);
  logits[tid] = acc;
}

__global__ void topk_kernel(const float* __restrict__ logits, int* __restrict__ sel,
                            float* __restrict__ wcomb, float* __restrict__ prob_sums,
                            int* __restrict__ counts_raw, float* __restrict__ z2sum) {
  __shared__ float ps[16];
  __shared__ int   cs[16];
  __shared__ float zs;
  int tid = threadIdx.x;
  if (tid < 16) { ps[tid] = 0.f; cs[tid] = 0; }
  if (tid == 0) zs = 0.f;
  __syncthreads();
  int t = blockIdx.x * 256 + tid;
  float l[16];
#pragma unroll
  for (int e = 0; e < 16; e++) l[e] = logits[(size_t)t * 16 + e];
  float m1 = l[0]; int e1 = 0;
#pragma unroll
  for (int e = 1; e < 16; e++) if (l[e] > m1) { m1 = l[e]; e1 = e; }
  float m2 = -3.4e38f; int e2 = 0;
#pragma unroll
  for (int e = 0; e < 16; e++) if (e != e1 && l[e] > m2) { m2 = l[e]; e2 = e; }
  float b  = __expf(m2 - m1);
  float w1 = 1.f / (1.f + b);
  sel[t * 2] = e1; sel[t * 2 + 1] = e2;
  wcomb[t * 2] = w1; wcomb[t * 2 + 1] = 1.f - w1;
  float s = 0.f;
  float pexp[16];
#pragma unroll
  for (int e = 0; e < 16; e++) { pexp[e] = __expf(l[e] - m1); s += pexp[e]; }
  float inv = 1.f / s;
#pragma unroll
  for (int e = 0; e < 16; e++) atomicAdd(&ps[e], pexp[e] * inv);
  atomicAdd(&cs[e1], 1); atomicAdd(&cs[e2], 1);
  float z = m1 + __logf(s);
  atomicAdd(&zs, z * z);
  __syncthreads();
  if (tid < 16) { atomicAdd(&prob_sums[tid], ps[tid]); atomicAdd(&counts_raw[tid], cs[tid]); }
  if (tid == 0) atomicAdd(z2sum, zs);
}

__global__ void hist_kernel(const int* __restrict__ sel, int* __restrict__ bhist) {
  __shared__ int h[16];
  int tid = threadIdx.x;
  if (tid < 16) h[tid] = 0;
  __syncthreads();
  atomicAdd(&h[sel[blockIdx.x * 256 + tid]], 1);
  __syncthreads();
  if (tid < 16) bhist[blockIdx.x * 16 + tid] = h[tid];
}

__global__ void scan_kernel(const int* __restrict__ bhist, int* __restrict__ bbase,
                            int* __restrict__ capc) {
  int e = threadIdx.x;
  if (e >= 16) return;
  int run = 0;
  for (int b = 0; b < 256; b++) { bbase[b * 16 + e] = run; run += bhist[b * 16 + e]; }
  capc[e] = run < CAP ? run : CAP;
}

__global__ void rank_kernel(const int* __restrict__ sel, const int* __restrict__ bbase,
                            int* __restrict__ pos_tk, int* __restrict__ scat) {
  __shared__ int se[256];
  int i = threadIdx.x;
  int a = blockIdx.x * 256 + i;
  int e = sel[a];
  se[i] = e;
  __syncthreads();
  int r = 0;
  for (int j = 0; j < i; j++) r += (se[j] == e) ? 1 : 0;
  int pos = bbase[blockIdx.x * 16 + e] + r;
  if (pos < CAP) { pos_tk[a] = pos; scat[e * CAP + pos] = a >> 1; }
  else           { pos_tk[a] = -1; }
}

// ---------------- GEMM1: expert_in @ w_up_gate, fused SiLU*up ----------------
// tiles: M=128 (c), N=64 (i) for BOTH gate and up; BK=64; 4 waves, each wave
// 64x32 per output via 4x2 grid of 16x16x32 mfma, 2 k-substeps per tile.
// LDS rows are 128B; XOR-swizzle slot ^= (row&7) applied on the GLOBAL source
// (gld_lds writes linearly) and re-applied on the ds_read side (rule 21).
// Read groups of 16 lanes then hit each bank-group exactly 2x (free, m136).

__global__ __launch_bounds__(256) void gemm1_kernel(
    const unsigned short* __restrict__ xb, const unsigned short* __restrict__ wtg,
    const int* __restrict__ scat, const int* __restrict__ capc,
    const unsigned short* __restrict__ zrow, unsigned short* __restrict__ act) {
  int e = blockIdx.z, ct = blockIdx.x, it = blockIdx.y;
  if (ct * 128 >= capc[e]) return;
  __shared__ __align__(16) unsigned short As[128 * 64];   // 16 KB
  __shared__ __align__(16) unsigned short Bg[64 * 64];    //  8 KB
  __shared__ __align__(16) unsigned short Bu[64 * 64];    //  8 KB
  const int t = threadIdx.x, w = t >> 6, l = t & 63;
  const int lr8   = l >> 3;                  // row within 8-row staging group
  const int koffs = ((l & 7) ^ lr8) * 8;     // pre-swizzled global 16B-slot

  // A row pointers: rows w*32 + j*8 + lr8 (gathered tokens)
  const unsigned short* aptr[4];
#pragma unroll
  for (int j = 0; j < 4; j++) {
    int c0 = ct * 128 + w * 32 + j * 8 + lr8;
    int tok = scat[e * CAP + c0];
    aptr[j] = (tok >= 0 ? xb + (size_t)tok * DIM : zrow) + koffs;
  }
  const unsigned short* bgp[2];
  const unsigned short* bup[2];
#pragma unroll
  for (int j = 0; j < 2; j++) {
    int n0 = it * 64 + w * 16 + j * 8 + lr8;
    bgp[j] = wtg + ((size_t)e * (2 * IDIM) + n0) * DIM + koffs;
    bup[j] = bgp[j] + (size_t)IDIM * DIM;
  }

  floatx4 accg[8], accu[8];
#pragma unroll
  for (int i = 0; i < 8; i++) {
    accg[i] = (floatx4){0.f, 0.f, 0.f, 0.f};
    accu[i] = (floatx4){0.f, 0.f, 0.f, 0.f};
  }
  const int wm = w >> 1, wn = w & 1;
  const int rl = l & 15, lq = l >> 4, sx = l & 7;

  for (int k0 = 0; k0 < DIM; k0 += 64) {
    __syncthreads();
#pragma unroll
    for (int j = 0; j < 4; j++)
      gld_lds16(aptr[j] + k0, (char*)As + w * 4096 + j * 1024);
#pragma unroll
    for (int j = 0; j < 2; j++) {
      gld_lds16(bgp[j] + k0, (char*)Bg + w * 2048 + j * 1024);
      gld_lds16(bup[j] + k0, (char*)Bu + w * 2048 + j * 1024);
    }
    __syncthreads();
#pragma unroll
    for (int ks = 0; ks < 2; ks++) {
      const int slot = ((ks * 4 + lq) ^ sx) * 8;
      short8 af[4], bgf[2], buf2[2];
#pragma unroll
      for (int mi = 0; mi < 4; mi++)
        af[mi] = *(const short8*)(As + (wm * 64 + mi * 16 + rl) * 64 + slot);
#pragma unroll
      for (int ni = 0; ni < 2; ni++) {
        bgf[ni]  = *(const short8*)(Bg + (wn * 32 + ni * 16 + rl) * 64 + slot);
        buf2[ni] = *(const short8*)(Bu + (wn * 32 + ni * 16 + rl) * 64 + slot);
      }
#pragma unroll
      for (int mi = 0; mi < 4; mi++)
#pragma unroll
        for (int ni = 0; ni < 2; ni++) {
          accg[mi * 2 + ni] = __builtin_amdgcn_mfma_f32_16x16x32_bf16(af[mi], bgf[ni],  accg[mi * 2 + ni], 0, 0, 0);
          accu[mi * 2 + ni] = __builtin_amdgcn_mfma_f32_16x16x32_bf16(af[mi], buf2[ni], accu[mi * 2 + ni], 0, 0, 0);
        }
    }
  }

  size_t abase = ((size_t)e * CAP + (size_t)ct * 128) * IDIM + (size_t)it * 64;
#pragma unroll
  for (int mi = 0; mi < 4; mi++)
#pragma unroll
    for (int reg = 0; reg < 4; reg++) {
      int m = wm * 64 + mi * 16 + lq * 4 + reg;
#pragma unroll
      for (int ni = 0; ni < 2; ni++) {
        int n = wn * 32 + ni * 16 + (l & 15);
        float g = accg[mi * 2 + ni][reg];
        float u = accu[mi * 2 + ni][reg];
        float a = g / (1.f + __expf(-g)) * u;   // silu(g)*u
        act[abase + (size_t)m * IDIM + n] = f2bf(a);
      }
    }
}

// ---------------- GEMM2: act @ w_down ----------------
// same structure: M=128, N=64, BK=64, swizzled LDS.

__global__ __launch_bounds__(256) void gemm2_kernel(
    const unsigned short* __restrict__ act, const unsigned short* __restrict__ wtd,
    const int* __restrict__ capc, unsigned short* __restrict__ eout) {
  int e = blockIdx.z, ct = blockIdx.x, it = blockIdx.y;
  if (ct * 128 >= capc[e]) return;
  __shared__ __align__(16) unsigned short As[128 * 64];   // 16 KB
  __shared__ __align__(16) unsigned short Bs[64 * 64];    //  8 KB
  const int t = threadIdx.x, w = t >> 6, l = t & 63;
  const int lr8   = l >> 3;
  const int koffs = ((l & 7) ^ lr8) * 8;

  const unsigned short* aptr[4];
#pragma unroll
  for (int j = 0; j < 4; j++)
    aptr[j] = act + ((size_t)e * CAP + ct * 128 + w * 32 + j * 8 + lr8) * IDIM + koffs;
  const unsigned short* bptr[2];
#pragma unroll
  for (int j = 0; j < 2; j++)
    bptr[j] = wtd + ((size_t)e * DIM + it * 64 + w * 16 + j * 8 + lr8) * IDIM + koffs;

  floatx4 acc[8];
#pragma unroll
  for (int i = 0; i < 8; i++) acc[i] = (floatx4){0.f, 0.f, 0.f, 0.f};
  const int wm = w >> 1, wn = w & 1;
  const int rl = l & 15, lq = l >> 4, sx = l & 7;

  for (int k0 = 0; k0 < IDIM; k0 += 64) {
    __syncthreads();
#pragma unroll
    for (int j = 0; j < 4; j++)
      gld_lds16(aptr[j] + k0, (char*)As + w * 4096 + j * 1024);
#pragma unroll
    for (int j = 0; j < 2; j++)
      gld_lds16(bptr[j] + k0, (char*)Bs + w * 2048 + j * 1024);
    __syncthreads();
#pragma unroll
    for (int ks = 0; ks < 2; ks++) {
      const int slot = ((ks * 4 + lq) ^ sx) * 8;
      short8 af[4], bf2[2];
#pragma unroll
      for (int mi = 0; mi < 4; mi++)
        af[mi] = *(const short8*)(As + (wm * 64 + mi * 16 + rl) * 64 + slot);
#pragma unroll
      for (int ni = 0; ni < 2; ni++)
        bf2[ni] = *(const short8*)(Bs + (wn * 32 + ni * 16 + rl) * 64 + slot);
#pragma unroll
      for (int mi = 0; mi < 4; mi++)
#pragma unroll
        for (int ni = 0; ni < 2; ni++)
          acc[mi * 2 + ni] = __builtin_amdgcn_mfma_f32_16x16x32_bf16(af[mi], bf2[ni], acc[mi * 2 + ni], 0, 0, 0);
    }
  }

  size_t obase = ((size_t)e * CAP + (size_t)ct * 128) * DIM + (size_t)it * 64;
#pragma unroll
  for (int mi = 0; mi < 4; mi++)
#pragma unroll
    for (int reg = 0; reg < 4; reg++) {
      int m = wm * 64 + mi * 16 + lq * 4 + reg;
#pragma unroll
      for (int ni = 0; ni < 2; ni++) {
        int n = wn * 32 + ni * 16 + (l & 15);
        eout[obase + (size_t)m * DIM + n] = f2bf(acc[mi * 2 + ni][reg]);
      }
    }
}

// ---------------- gather + weighted combine ----------------

__global__ void combine_kernel(const unsigned short* __restrict__ eout,
                               const int* __restrict__ sel, const int* __restrict__ pos_tk,
                               const float* __restrict__ wcomb, float* __restrict__ routed) {
  int tok = blockIdx.x;
  int d = threadIdx.x * 4;
  float a0 = 0.f, a1 = 0.f, a2 = 0.f, a3 = 0.f;
#pragma unroll
  for (int s = 0; s < 2; s++) {
    int a = tok * 2 + s;
    int p = pos_tk[a];
    if (p >= 0) {
      int e = sel[a];
      float wgt = wcomb[a];
      const unsigned short* row = eout + ((size_t)e * CAP + p) * DIM + d;
      ushort4 r = *(const ushort4*)row;
      a0 += wgt * bf2f(r.x); a1 += wgt * bf2f(r.y);
      a2 += wgt * bf2f(r.z); a3 += wgt * bf2f(r.w);
    }
  }
  float4 o = {a0, a1, a2, a3};
  *(float4*)(routed + (size_t)tok * DIM + d) = o;
}

__global__ void finalize_kernel(const int* __restrict__ counts_raw, const float* __restrict__ psums,
                                const float* __restrict__ z2sum, float* __restrict__ tail) {
  if (threadIdx.x != 0 || blockIdx.x != 0) return;
  float ent = 0.f, lb = 0.f;
  for (int e = 0; e < 16; e++) {
    float c = (float)counts_raw[e];
    tail[e] = c;
    float frac = c / 65536.f;
    ent -= frac * logf(frac + 1e-6f);
    lb += frac * 2.f * (psums[e] / 32768.f);
  }
  tail[16] = ent;
  tail[17] = 16.f * lb;
  tail[18] = z2sum[0] / 32768.f;
}

// ---------------- launch ----------------

extern "C" void kernel_launch(void* const* d_in, const int* in_sizes, int n_in,
                              void* d_out, int out_size, void* d_ws, size_t ws_size,
                              hipStream_t stream) {
  (void)in_sizes; (void)n_in; (void)out_size; (void)ws_size;
  const float* x         = (const float*)d_in[0];
  const float* router    = (const float*)d_in[1];
  const float* w_up_gate = (const float*)d_in[2];
  const float* w_down    = (const float*)d_in[3];
  float* out = (float*)d_out;

  char* p = (char*)d_ws;
  size_t off = 0;
  auto alc = [&](size_t n) { void* r = p + off; off += (n + 255) & ~(size_t)255; return r; };

  unsigned short* xb   = (unsigned short*)alc((size_t)T_TOK * DIM * 2);         //  64 MB
  unsigned short* wtg  = (unsigned short*)alc((size_t)NE * 2 * IDIM * DIM * 2); // 184.5 MB
  unsigned short* wtd  = (unsigned short*)alc((size_t)NE * DIM * IDIM * 2);     //  92.3 MB
  unsigned short* act  = (unsigned short*)alc((size_t)NE * CAP * IDIM * 2);     // 461.4 MB
  unsigned short* eout = (unsigned short*)alc((size_t)NE * CAP * DIM * 2);      // 167.8 MB
  float* logits = (float*)alc((size_t)T_TOK * NE * 4);
  int*   sel    = (int*)alc((size_t)TKA * 4);
  float* wcomb  = (float*)alc((size_t)TKA * 4);
  int*   pos_tk = (int*)alc((size_t)TKA * 4);
  int*   scat   = (int*)alc((size_t)NE * CAP * 4);
  int*   bhist  = (int*)alc(256 * 16 * 4);
  int*   bbase  = (int*)alc(256 * 16 * 4);
  int*   capc   = (int*)alc(64);
  int*   counts_raw = (int*)alc(64);
  float* psums  = (float*)alc(64);
  float* z2     = (float*)alc(64);
  unsigned short* zrow = (unsigned short*)alc(DIM * 2);

  hipMemsetAsync(counts_raw, 0, 64, stream);
  hipMemsetAsync(psums, 0, 64, stream);
  hipMemsetAsync(z2, 0, 64, stream);
  hipMemsetAsync(scat, 0xFF, (size_t)NE * CAP * 4, stream);
  hipMemsetAsync(zrow, 0, DIM * 2, stream);

  cvtx_kernel<<<T_TOK * DIM / (256 * 8), 256, 0, stream>>>(x, xb);
  transpose_cvt<<<dim3(2 * IDIM / 64, DIM / 64, NE), 256, 0, stream>>>(w_up_gate, wtg, DIM, 2 * IDIM);
  transpose_cvt<<<dim3(DIM / 64, IDIM / 64, NE), 256, 0, stream>>>(w_down, wtd, IDIM, DIM);

  router_kernel<<<T_TOK * NE / 256, 256, 0, stream>>>(x, router, logits);
  topk_kernel<<<T_TOK / 256, 256, 0, stream>>>(logits, sel, wcomb, psums, counts_raw, z2);
  hist_kernel<<<TKA / 256, 256, 0, stream>>>(sel, bhist);
  scan_kernel<<<1, 64, 0, stream>>>(bhist, bbase, capc);
  rank_kernel<<<TKA / 256, 256, 0, stream>>>(sel, bbase, pos_tk, scat);

  gemm1_kernel<<<dim3(CAP / 128, IDIM / 64, NE), 256, 0, stream>>>(xb, wtg, scat, capc, zrow, act);
  gemm2_kernel<<<dim3(CAP / 128, DIM / 64, NE), 256, 0, stream>>>(act, wtd, capc, eout);

  combine_kernel<<<T_TOK, 256, 0, stream>>>(eout, sel, pos_tk, wcomb, out);
  finalize_kernel<<<1, 64, 0, stream>>>(counts_raw, psums, z2, out + (size_t)T_TOK * DIM);
}

// Round 2
// 2351.024 us; speedup vs baseline: 1.1486x; 1.0557x over previous
//
#include <hip/hip_runtime.h>
#include <math.h>

#define T_TOK 32768
#define TKA   65536
#define DIM   1024
#define NE    16
#define IDIM  2816
#define CAP   5120

typedef short short8 __attribute__((ext_vector_type(8)));
typedef float floatx4 __attribute__((ext_vector_type(4)));

__device__ __forceinline__ unsigned short f2bf(float f) {
  unsigned int u = __float_as_uint(f);
  u = u + 0x7FFFu + ((u >> 16) & 1u);   // round-to-nearest-even
  return (unsigned short)(u >> 16);
}
__device__ __forceinline__ float bf2f(unsigned short h) {
  return __uint_as_float(((unsigned int)h) << 16);
}

// async global->LDS, 16B per lane. LDS dst must be the wave-uniform base;
// HW adds lane*16 (m104/m108 semantics).
__device__ __forceinline__ void gld_lds16(const void* g, void* l) {
  __builtin_amdgcn_global_load_lds(
      (const __attribute__((address_space(1))) unsigned int*)(unsigned long long)g,
      (__attribute__((address_space(3))) unsigned int*)(unsigned int)(unsigned long long)l,
      16, 0, 0);
}

// ---------------- pre-pass: conversions / transposes ----------------

__global__ void cvtx_kernel(const float* __restrict__ in, unsigned short* __restrict__ out) {
  size_t i = ((size_t)blockIdx.x * 256 + threadIdx.x) * 8;
  float4 a = *(const float4*)(in + i);
  float4 b = *(const float4*)(in + i + 4);
  short8 v;
  v[0] = (short)f2bf(a.x); v[1] = (short)f2bf(a.y); v[2] = (short)f2bf(a.z); v[3] = (short)f2bf(a.w);
  v[4] = (short)f2bf(b.x); v[5] = (short)f2bf(b.y); v[6] = (short)f2bf(b.z); v[7] = (short)f2bf(b.w);
  *(short8*)(out + i) = v;
}

// in: [e][R][Cin] fp32  ->  out: [e][Cin][R] bf16   (R, Cin multiples of 64)
__global__ void transpose_cvt(const float* __restrict__ in, unsigned short* __restrict__ out,
                              int R, int Cin) {
  int e = blockIdx.z;
  size_t base = (size_t)e * R * Cin;
  int ct = blockIdx.x;   // tile over input cols
  int rt = blockIdx.y;   // tile over input rows
  __shared__ unsigned short Ts[64][72];
  int tx = threadIdx.x & 63, ty = threadIdx.x >> 6;
#pragma unroll
  for (int j = 0; j < 16; j++) {
    int r = rt * 64 + ty + j * 4;
    int c = ct * 64 + tx;
    Ts[tx][ty + j * 4] = f2bf(in[base + (size_t)r * Cin + c]);
  }
  __syncthreads();
#pragma unroll
  for (int j = 0; j < 16; j++) {
    int cl = ty + j * 4;
    out[base + (size_t)(ct * 64 + cl) * R + rt * 64 + tx] = Ts[cl][tx];
  }
}

// ---------------- router / stats / capacity ----------------

__global__ void router_kernel(const float* __restrict__ x, const float* __restrict__ router,
                              float* __restrict__ logits) {
  int tid = blockIdx.x * 256 + threadIdx.x;   // 524288 = T*16 threads
  int tk = tid >> 4, e = tid & 15;
  const float* xr = x + (size_t)tk * DIM;
  float acc = 0.f;
#pragma unroll 8
  for (int d = 0; d < DIM; d++) acc = fmaf(xr[d], router[d * NE + e], acc);
  logits[tid] = acc;
}

__global__ void topk_kernel(const float* __restrict__ logits, int* __restrict__ sel,
                            float* __restrict__ wcomb, float* __restrict__ prob_sums,
                            int* __restrict__ counts_raw, float* __restrict__ z2sum) {
  __shared__ float ps[16];
  __shared__ int   cs[16];
  __shared__ float zs;
  int tid = threadIdx.x;
  if (tid < 16) { ps[tid] = 0.f; cs[tid] = 0; }
  if (tid == 0) zs = 0.f;
  __syncthreads();
  int t = blockIdx.x * 256 + tid;
  float l[16];
#pragma unroll
  for (int e = 0; e < 16; e++) l[e] = logits[(size_t)t * 16 + e];
  float m1 = l[0]; int e1 = 0;
#pragma unroll
  for (int e = 1; e < 16; e++) if (l[e] > m1) { m1 = l[e]; e1 = e; }
  float m2 = -3.4e38f; int e2 = 0;
#pragma unroll
  for (int e = 0; e < 16; e++) if (e != e1 && l[e] > m2) { m2 = l[e]; e2 = e; }
  float b  = __expf(m2 - m1);
  float w1 = 1.f / (1.f + b);
  sel[t * 2] = e1; sel[t * 2 + 1] = e2;
  wcomb[t * 2] = w1; wcomb[t * 2 + 1] = 1.f - w1;
  float s = 0.f;
  float pexp[16];
#pragma unroll
  for (int e = 0; e < 16; e++) { pexp[e] = __expf(l[e] - m1); s += pexp[e]; }
  float inv = 1.f / s;
#pragma unroll
  for (int e = 0; e < 16; e++) atomicAdd(&ps[e], pexp[e] * inv);
  atomicAdd(&cs[e1], 1); atomicAdd(&cs[e2], 1);
  float z = m1 + __logf(s);
  atomicAdd(&zs, z * z);
  __syncthreads();
  if (tid < 16) { atomicAdd(&prob_sums[tid], ps[tid]); atomicAdd(&counts_raw[tid], cs[tid]); }
  if (tid == 0) atomicAdd(z2sum, zs);
}

__global__ void hist_kernel(const int* __restrict__ sel, int* __restrict__ bhist) {
  __shared__ int h[16];
  int tid = threadIdx.x;
  if (tid < 16) h[tid] = 0;
  __syncthreads();
  atomicAdd(&h[sel[blockIdx.x * 256 + tid]], 1);
  __syncthreads();
  if (tid < 16) bhist[blockIdx.x * 16 + tid] = h[tid];
}

// load all 4096 ints into LDS coalesced, then 16 lanes scan from LDS
__global__ void scan_kernel(const int* __restrict__ bhist, int* __restrict__ bbase,
                            int* __restrict__ capc) {
  __shared__ int h[256 * 16];
  int t = threadIdx.x;
  for (int i = t; i < 256 * 16 / 4; i += 256)
    ((int4*)h)[i] = ((const int4*)bhist)[i];
  __syncthreads();
  if (t < 16) {
    int run = 0;
    for (int b = 0; b < 256; b++) { bbase[b * 16 + t] = run; run += h[b * 16 + t]; }
    capc[t] = run < CAP ? run : CAP;
  }
}

__global__ void rank_kernel(const int* __restrict__ sel, const int* __restrict__ bbase,
                            int* __restrict__ pos_tk, int* __restrict__ scat) {
  __shared__ int se[256];
  int i = threadIdx.x;
  int a = blockIdx.x * 256 + i;
  int e = sel[a];
  se[i] = e;
  __syncthreads();
  int r = 0;
  for (int j = 0; j < i; j++) r += (se[j] == e) ? 1 : 0;
  int pos = bbase[blockIdx.x * 16 + e] + r;
  if (pos < CAP) { pos_tk[a] = pos; scat[e * CAP + pos] = a >> 1; }
  else           { pos_tk[a] = -1; }
}

// ---------------- GEMM1: expert_in @ w_up_gate, fused SiLU*up ----------------
// tiles: M=128 (c), N=64 (i) for BOTH gate and up; BK=64; 4 waves, each wave
// 64x32 per output via 4x2 grid of 16x16x32 mfma, 2 k-substeps per tile.
// XOR-swizzled LDS (slot ^= row&7) via pre-swizzled global source (rule 21).
// Double-buffered 2-phase pipeline (T3 minimum): stage(t+1) BEFORE compute(t),
// single __syncthreads per K-tile -> load latency hides under MFMA.

__global__ __launch_bounds__(256) void gemm1_kernel(
    const unsigned short* __restrict__ xb, const unsigned short* __restrict__ wtg,
    const int* __restrict__ scat, const int* __restrict__ capc,
    const unsigned short* __restrict__ zrow, unsigned short* __restrict__ act) {
  int e = blockIdx.z, ct = blockIdx.x, it = blockIdx.y;
  if (ct * 128 >= capc[e]) return;
  __shared__ __align__(16) unsigned short As0[128 * 64], As1[128 * 64];  // 16 KB each
  __shared__ __align__(16) unsigned short Bg0[64 * 64],  Bg1[64 * 64];   //  8 KB each
  __shared__ __align__(16) unsigned short Bu0[64 * 64],  Bu1[64 * 64];   //  8 KB each
  const int t = threadIdx.x, w = t >> 6, l = t & 63;
  const int lr8   = l >> 3;                  // row within 8-row staging group
  const int koffs = ((l & 7) ^ lr8) * 8;     // pre-swizzled global 16B-slot

  const unsigned short* aptr[4];
#pragma unroll
  for (int j = 0; j < 4; j++) {
    int c0 = ct * 128 + w * 32 + j * 8 + lr8;
    int tok = scat[e * CAP + c0];
    aptr[j] = (tok >= 0 ? xb + (size_t)tok * DIM : zrow) + koffs;
  }
  const unsigned short* bgp[2];
  const unsigned short* bup[2];
#pragma unroll
  for (int j = 0; j < 2; j++) {
    int n0 = it * 64 + w * 16 + j * 8 + lr8;
    bgp[j] = wtg + ((size_t)e * (2 * IDIM) + n0) * DIM + koffs;
    bup[j] = bgp[j] + (size_t)IDIM * DIM;
  }

  floatx4 accg[8], accu[8];
#pragma unroll
  for (int i = 0; i < 8; i++) {
    accg[i] = (floatx4){0.f, 0.f, 0.f, 0.f};
    accu[i] = (floatx4){0.f, 0.f, 0.f, 0.f};
  }
  const int wm = w >> 1, wn = w & 1;
  const int rl = l & 15, lq = l >> 4, sx = l & 7;

  auto stage = [&](int k0, unsigned short* As, unsigned short* Bg, unsigned short* Bu) {
#pragma unroll
    for (int j = 0; j < 4; j++)
      gld_lds16(aptr[j] + k0, (char*)As + w * 4096 + j * 1024);
#pragma unroll
    for (int j = 0; j < 2; j++) {
      gld_lds16(bgp[j] + k0, (char*)Bg + w * 2048 + j * 1024);
      gld_lds16(bup[j] + k0, (char*)Bu + w * 2048 + j * 1024);
    }
  };
  auto compute = [&](const unsigned short* As, const unsigned short* Bg,
                     const unsigned short* Bu) {
#pragma unroll
    for (int ks = 0; ks < 2; ks++) {
      const int slot = ((ks * 4 + lq) ^ sx) * 8;
      short8 af[4], bgf[2], buf2[2];
#pragma unroll
      for (int mi = 0; mi < 4; mi++)
        af[mi] = *(const short8*)(As + (wm * 64 + mi * 16 + rl) * 64 + slot);
#pragma unroll
      for (int ni = 0; ni < 2; ni++) {
        bgf[ni]  = *(const short8*)(Bg + (wn * 32 + ni * 16 + rl) * 64 + slot);
        buf2[ni] = *(const short8*)(Bu + (wn * 32 + ni * 16 + rl) * 64 + slot);
      }
#pragma unroll
      for (int mi = 0; mi < 4; mi++)
#pragma unroll
        for (int ni = 0; ni < 2; ni++) {
          accg[mi * 2 + ni] = __builtin_amdgcn_mfma_f32_16x16x32_bf16(af[mi], bgf[ni],  accg[mi * 2 + ni], 0, 0, 0);
          accu[mi * 2 + ni] = __builtin_amdgcn_mfma_f32_16x16x32_bf16(af[mi], buf2[ni], accu[mi * 2 + ni], 0, 0, 0);
        }
    }
  };

  stage(0, As0, Bg0, Bu0);
  __syncthreads();
  for (int k0 = 0; k0 < DIM; k0 += 128) {
    stage(k0 + 64, As1, Bg1, Bu1);       // prefetch odd tile
    compute(As0, Bg0, Bu0);              // compute even tile
    __syncthreads();                     // odd tile visible; even buffers free
    if (k0 + 128 < DIM) stage(k0 + 128, As0, Bg0, Bu0);
    compute(As1, Bg1, Bu1);
    __syncthreads();
  }

  size_t abase = ((size_t)e * CAP + (size_t)ct * 128) * IDIM + (size_t)it * 64;
#pragma unroll
  for (int mi = 0; mi < 4; mi++)
#pragma unroll
    for (int reg = 0; reg < 4; reg++) {
      int m = wm * 64 + mi * 16 + lq * 4 + reg;
#pragma unroll
      for (int ni = 0; ni < 2; ni++) {
        int n = wn * 32 + ni * 16 + (l & 15);
        float g = accg[mi * 2 + ni][reg];
        float u = accu[mi * 2 + ni][reg];
        float a = g / (1.f + __expf(-g)) * u;   // silu(g)*u
        act[abase + (size_t)m * IDIM + n] = f2bf(a);
      }
    }
}

// ---------------- GEMM2: act @ w_down ----------------
// same structure: M=128, N=64, BK=64, swizzled LDS, double-buffered pipeline.

__global__ __launch_bounds__(256) void gemm2_kernel(
    const unsigned short* __restrict__ act, const unsigned short* __restrict__ wtd,
    const int* __restrict__ capc, unsigned short* __restrict__ eout) {
  int e = blockIdx.z, ct = blockIdx.x, it = blockIdx.y;
  if (ct * 128 >= capc[e]) return;
  __shared__ __align__(16) unsigned short As0[128 * 64], As1[128 * 64];  // 16 KB each
  __shared__ __align__(16) unsigned short Bs0[64 * 64],  Bs1[64 * 64];   //  8 KB each
  const int t = threadIdx.x, w = t >> 6, l = t & 63;
  const int lr8   = l >> 3;
  const int koffs = ((l & 7) ^ lr8) * 8;

  const unsigned short* aptr[4];
#pragma unroll
  for (int j = 0; j < 4; j++)
    aptr[j] = act + ((size_t)e * CAP + ct * 128 + w * 32 + j * 8 + lr8) * IDIM + koffs;
  const unsigned short* bptr[2];
#pragma unroll
  for (int j = 0; j < 2; j++)
    bptr[j] = wtd + ((size_t)e * DIM + it * 64 + w * 16 + j * 8 + lr8) * IDIM + koffs;

  floatx4 acc[8];
#pragma unroll
  for (int i = 0; i < 8; i++) acc[i] = (floatx4){0.f, 0.f, 0.f, 0.f};
  const int wm = w >> 1, wn = w & 1;
  const int rl = l & 15, lq = l >> 4, sx = l & 7;

  auto stage = [&](int k0, unsigned short* As, unsigned short* Bs) {
#pragma unroll
    for (int j = 0; j < 4; j++)
      gld_lds16(aptr[j] + k0, (char*)As + w * 4096 + j * 1024);
#pragma unroll
    for (int j = 0; j < 2; j++)
      gld_lds16(bptr[j] + k0, (char*)Bs + w * 2048 + j * 1024);
  };
  auto compute = [&](const unsigned short* As, const unsigned short* Bs) {
#pragma unroll
    for (int ks = 0; ks < 2; ks++) {
      const int slot = ((ks * 4 + lq) ^ sx) * 8;
      short8 af[4], bf2[2];
#pragma unroll
      for (int mi = 0; mi < 4; mi++)
        af[mi] = *(const short8*)(As + (wm * 64 + mi * 16 + rl) * 64 + slot);
#pragma unroll
      for (int ni = 0; ni < 2; ni++)
        bf2[ni] = *(const short8*)(Bs + (wn * 32 + ni * 16 + rl) * 64 + slot);
#pragma unroll
      for (int mi = 0; mi < 4; mi++)
#pragma unroll
        for (int ni = 0; ni < 2; ni++)
          acc[mi * 2 + ni] = __builtin_amdgcn_mfma_f32_16x16x32_bf16(af[mi], bf2[ni], acc[mi * 2 + ni], 0, 0, 0);
    }
  };

  stage(0, As0, Bs0);
  __syncthreads();
  for (int k0 = 0; k0 < IDIM; k0 += 128) {
    stage(k0 + 64, As1, Bs1);
    compute(As0, Bs0);
    __syncthreads();
    if (k0 + 128 < IDIM) stage(k0 + 128, As0, Bs0);
    compute(As1, Bs1);
    __syncthreads();
  }

  size_t obase = ((size_t)e * CAP + (size_t)ct * 128) * DIM + (size_t)it * 64;
#pragma unroll
  for (int mi = 0; mi < 4; mi++)
#pragma unroll
    for (int reg = 0; reg < 4; reg++) {
      int m = wm * 64 + mi * 16 + lq * 4 + reg;
#pragma unroll
      for (int ni = 0; ni < 2; ni++) {
        int n = wn * 32 + ni * 16 + (l & 15);
        eout[obase + (size_t)m * DIM + n] = f2bf(acc[mi * 2 + ni][reg]);
      }
    }
}

// ---------------- gather + weighted combine ----------------

__global__ void combine_kernel(const unsigned short* __restrict__ eout,
                               const int* __restrict__ sel, const int* __restrict__ pos_tk,
                               const float* __restrict__ wcomb, float* __restrict__ routed) {
  int tok = blockIdx.x;
  int d = threadIdx.x * 4;
  float a0 = 0.f, a1 = 0.f, a2 = 0.f, a3 = 0.f;
#pragma unroll
  for (int s = 0; s < 2; s++) {
    int a = tok * 2 + s;
    int p = pos_tk[a];
    if (p >= 0) {
      int e = sel[a];
      float wgt = wcomb[a];
      const unsigned short* row = eout + ((size_t)e * CAP + p) * DIM + d;
      ushort4 r = *(const ushort4*)row;
      a0 += wgt * bf2f(r.x); a1 += wgt * bf2f(r.y);
      a2 += wgt * bf2f(r.z); a3 += wgt * bf2f(r.w);
    }
  }
  float4 o = {a0, a1, a2, a3};
  *(float4*)(routed + (size_t)tok * DIM + d) = o;
}

__global__ void finalize_kernel(const int* __restrict__ counts_raw, const float* __restrict__ psums,
                                const float* __restrict__ z2sum, float* __restrict__ tail) {
  if (threadIdx.x != 0 || blockIdx.x != 0) return;
  float ent = 0.f, lb = 0.f;
  for (int e = 0; e < 16; e++) {
    float c = (float)counts_raw[e];
    tail[e] = c;
    float frac = c / 65536.f;
    ent -= frac * logf(frac + 1e-6f);
    lb += frac * 2.f * (psums[e] / 32768.f);
  }
  tail[16] = ent;
  tail[17] = 16.f * lb;
  tail[18] = z2sum[0] / 32768.f;
}

// ---------------- launch ----------------

extern "C" void kernel_launch(void* const* d_in, const int* in_sizes, int n_in,
                              void* d_out, int out_size, void* d_ws, size_t ws_size,
                              hipStream_t stream) {
  (void)in_sizes; (void)n_in; (void)out_size; (void)ws_size;
  const float* x         = (const float*)d_in[0];
  const float* router    = (const float*)d_in[1];
  const float* w_up_gate = (const float*)d_in[2];
  const float* w_down    = (const float*)d_in[3];
  float* out = (float*)d_out;

  char* p = (char*)d_ws;
  size_t off = 0;
  auto alc = [&](size_t n) { void* r = p + off; off += (n + 255) & ~(size_t)255; return r; };

  unsigned short* xb   = (unsigned short*)alc((size_t)T_TOK * DIM * 2);         //  64 MB
  unsigned short* wtg  = (unsigned short*)alc((size_t)NE * 2 * IDIM * DIM * 2); // 184.5 MB
  unsigned short* wtd  = (unsigned short*)alc((size_t)NE * DIM * IDIM * 2);     //  92.3 MB
  unsigned short* act  = (unsigned short*)alc((size_t)NE * CAP * IDIM * 2);     // 461.4 MB
  unsigned short* eout = (unsigned short*)alc((size_t)NE * CAP * DIM * 2);      // 167.8 MB
  float* logits = (float*)alc((size_t)T_TOK * NE * 4);
  int*   sel    = (int*)alc((size_t)TKA * 4);
  float* wcomb  = (float*)alc((size_t)TKA * 4);
  int*   pos_tk = (int*)alc((size_t)TKA * 4);
  int*   scat   = (int*)alc((size_t)NE * CAP * 4);
  int*   bhist  = (int*)alc(256 * 16 * 4);
  int*   bbase  = (int*)alc(256 * 16 * 4);
  int*   capc   = (int*)alc(64);
  int*   counts_raw = (int*)alc(64);
  float* psums  = (float*)alc(64);
  float* z2     = (float*)alc(64);
  unsigned short* zrow = (unsigned short*)alc(DIM * 2);

  hipMemsetAsync(counts_raw, 0, 64, stream);
  hipMemsetAsync(psums, 0, 64, stream);
  hipMemsetAsync(z2, 0, 64, stream);
  hipMemsetAsync(scat, 0xFF, (size_t)NE * CAP * 4, stream);
  hipMemsetAsync(zrow, 0, DIM * 2, stream);

  cvtx_kernel<<<T_TOK * DIM / (256 * 8), 256, 0, stream>>>(x, xb);
  transpose_cvt<<<dim3(2 * IDIM / 64, DIM / 64, NE), 256, 0, stream>>>(w_up_gate, wtg, DIM, 2 * IDIM);
  transpose_cvt<<<dim3(DIM / 64, IDIM / 64, NE), 256, 0, stream>>>(w_down, wtd, IDIM, DIM);

  router_kernel<<<T_TOK * NE / 256, 256, 0, stream>>>(x, router, logits);
  topk_kernel<<<T_TOK / 256, 256, 0, stream>>>(logits, sel, wcomb, psums, counts_raw, z2);
  hist_kernel<<<TKA / 256, 256, 0, stream>>>(sel, bhist);
  scan_kernel<<<1, 256, 0, stream>>>(bhist, bbase, capc);
  rank_kernel<<<TKA / 256, 256, 0, stream>>>(sel, bbase, pos_tk, scat);

  gemm1_kernel<<<dim3(CAP / 128, IDIM / 64, NE), 256, 0, stream>>>(xb, wtg, scat, capc, zrow, act);
  gemm2_kernel<<<dim3(CAP / 128, DIM / 64, NE), 256, 0, stream>>>(act, wtd, capc, eout);

  combine_kernel<<<T_TOK, 256, 0, stream>>>(eout, sel, pos_tk, wcomb, out);
  finalize_kernel<<<1, 64, 0, stream>>>(counts_raw, psums, z2, out + (size_t)T_TOK * DIM);
}

// Round 3
// 2334.564 us; speedup vs baseline: 1.1567x; 1.0071x over previous
//
#include <hip/hip_runtime.h>
#include <math.h>

#define T_TOK 32768
#define TKA   65536
#define DIM   1024
#define NE    16
#define IDIM  2816
#define CAP   5120

typedef short short8 __attribute__((ext_vector_type(8)));
typedef float floatx4 __attribute__((ext_vector_type(4)));

__device__ __forceinline__ unsigned short f2bf(float f) {
  unsigned int u = __float_as_uint(f);
  u = u + 0x7FFFu + ((u >> 16) & 1u);   // round-to-nearest-even
  return (unsigned short)(u >> 16);
}
__device__ __forceinline__ float bf2f(unsigned short h) {
  return __uint_as_float(((unsigned int)h) << 16);
}

// async global->LDS, 16B per lane. LDS dst must be the wave-uniform base;
// HW adds lane*16 (m104/m108 semantics).
__device__ __forceinline__ void gld_lds16(const void* g, void* l) {
  __builtin_amdgcn_global_load_lds(
      (const __attribute__((address_space(1))) unsigned int*)(unsigned long long)g,
      (__attribute__((address_space(3))) unsigned int*)(unsigned int)(unsigned long long)l,
      16, 0, 0);
}

// Raw barriers with counted vmcnt (T4). sched_barrier(0) fences prevent
// MFMA/ds_read motion across the barrier (rule #18 hazard).
__device__ __forceinline__ void sbar() {
  __builtin_amdgcn_sched_barrier(0);
  asm volatile("" ::: "memory");
  __builtin_amdgcn_s_barrier();
  asm volatile("" ::: "memory");
  __builtin_amdgcn_sched_barrier(0);
}
__device__ __forceinline__ void sbar_vm8() {
  __builtin_amdgcn_sched_barrier(0);
  asm volatile("s_waitcnt vmcnt(8)" ::: "memory");
  __builtin_amdgcn_s_barrier();
  asm volatile("" ::: "memory");
  __builtin_amdgcn_sched_barrier(0);
}
__device__ __forceinline__ void sbar_vm6() {
  __builtin_amdgcn_sched_barrier(0);
  asm volatile("s_waitcnt vmcnt(6)" ::: "memory");
  __builtin_amdgcn_s_barrier();
  asm volatile("" ::: "memory");
  __builtin_amdgcn_sched_barrier(0);
}
__device__ __forceinline__ void sbar_vm0() {
  __builtin_amdgcn_sched_barrier(0);
  asm volatile("s_waitcnt vmcnt(0)" ::: "memory");
  __builtin_amdgcn_s_barrier();
  asm volatile("" ::: "memory");
  __builtin_amdgcn_sched_barrier(0);
}

// ---------------- pre-pass: conversions / transposes ----------------

__global__ void cvtx_kernel(const float* __restrict__ in, unsigned short* __restrict__ out) {
  size_t i = ((size_t)blockIdx.x * 256 + threadIdx.x) * 8;
  float4 a = *(const float4*)(in + i);
  float4 b = *(const float4*)(in + i + 4);
  short8 v;
  v[0] = (short)f2bf(a.x); v[1] = (short)f2bf(a.y); v[2] = (short)f2bf(a.z); v[3] = (short)f2bf(a.w);
  v[4] = (short)f2bf(b.x); v[5] = (short)f2bf(b.y); v[6] = (short)f2bf(b.z); v[7] = (short)f2bf(b.w);
  *(short8*)(out + i) = v;
}

// in: [e][R][Cin] fp32  ->  out: [e][Cin][R] bf16   (R, Cin multiples of 64)
__global__ void transpose_cvt(const float* __restrict__ in, unsigned short* __restrict__ out,
                              int R, int Cin) {
  int e = blockIdx.z;
  size_t base = (size_t)e * R * Cin;
  int ct = blockIdx.x;   // tile over input cols
  int rt = blockIdx.y;   // tile over input rows
  __shared__ unsigned short Ts[64][72];
  int tx = threadIdx.x & 63, ty = threadIdx.x >> 6;
#pragma unroll
  for (int j = 0; j < 16; j++) {
    int r = rt * 64 + ty + j * 4;
    int c = ct * 64 + tx;
    Ts[tx][ty + j * 4] = f2bf(in[base + (size_t)r * Cin + c]);
  }
  __syncthreads();
#pragma unroll
  for (int j = 0; j < 16; j++) {
    int cl = ty + j * 4;
    out[base + (size_t)(ct * 64 + cl) * R + rt * 64 + tx] = Ts[cl][tx];
  }
}

// ---------------- router / stats / capacity ----------------

__global__ void router_kernel(const float* __restrict__ x, const float* __restrict__ router,
                              float* __restrict__ logits) {
  int tid = blockIdx.x * 256 + threadIdx.x;   // 524288 = T*16 threads
  int tk = tid >> 4, e = tid & 15;
  const float* xr = x + (size_t)tk * DIM;
  float acc = 0.f;
#pragma unroll 8
  for (int d = 0; d < DIM; d++) acc = fmaf(xr[d], router[d * NE + e], acc);
  logits[tid] = acc;
}

__global__ void topk_kernel(const float* __restrict__ logits, int* __restrict__ sel,
                            float* __restrict__ wcomb, float* __restrict__ prob_sums,
                            int* __restrict__ counts_raw, float* __restrict__ z2sum) {
  __shared__ float ps[16];
  __shared__ int   cs[16];
  __shared__ float zs;
  int tid = threadIdx.x;
  if (tid < 16) { ps[tid] = 0.f; cs[tid] = 0; }
  if (tid == 0) zs = 0.f;
  __syncthreads();
  int t = blockIdx.x * 256 + tid;
  float l[16];
#pragma unroll
  for (int e = 0; e < 16; e++) l[e] = logits[(size_t)t * 16 + e];
  float m1 = l[0]; int e1 = 0;
#pragma unroll
  for (int e = 1; e < 16; e++) if (l[e] > m1) { m1 = l[e]; e1 = e; }
  float m2 = -3.4e38f; int e2 = 0;
#pragma unroll
  for (int e = 0; e < 16; e++) if (e != e1 && l[e] > m2) { m2 = l[e]; e2 = e; }
  float b  = __expf(m2 - m1);
  float w1 = 1.f / (1.f + b);
  sel[t * 2] = e1; sel[t * 2 + 1] = e2;
  wcomb[t * 2] = w1; wcomb[t * 2 + 1] = 1.f - w1;
  float s = 0.f;
  float pexp[16];
#pragma unroll
  for (int e = 0; e < 16; e++) { pexp[e] = __expf(l[e] - m1); s += pexp[e]; }
  float inv = 1.f / s;
#pragma unroll
  for (int e = 0; e < 16; e++) atomicAdd(&ps[e], pexp[e] * inv);
  atomicAdd(&cs[e1], 1); atomicAdd(&cs[e2], 1);
  float z = m1 + __logf(s);
  atomicAdd(&zs, z * z);
  __syncthreads();
  if (tid < 16) { atomicAdd(&prob_sums[tid], ps[tid]); atomicAdd(&counts_raw[tid], cs[tid]); }
  if (tid == 0) atomicAdd(z2sum, zs);
}

__global__ void hist_kernel(const int* __restrict__ sel, int* __restrict__ bhist) {
  __shared__ int h[16];
  int tid = threadIdx.x;
  if (tid < 16) h[tid] = 0;
  __syncthreads();
  atomicAdd(&h[sel[blockIdx.x * 256 + tid]], 1);
  __syncthreads();
  if (tid < 16) bhist[blockIdx.x * 16 + tid] = h[tid];
}

// load all 4096 ints into LDS coalesced, then 16 lanes scan from LDS
__global__ void scan_kernel(const int* __restrict__ bhist, int* __restrict__ bbase,
                            int* __restrict__ capc) {
  __shared__ int h[256 * 16];
  int t = threadIdx.x;
  for (int i = t; i < 256 * 16 / 4; i += 256)
    ((int4*)h)[i] = ((const int4*)bhist)[i];
  __syncthreads();
  if (t < 16) {
    int run = 0;
    for (int b = 0; b < 256; b++) { bbase[b * 16 + t] = run; run += h[b * 16 + t]; }
    capc[t] = run < CAP ? run : CAP;
  }
}

__global__ void rank_kernel(const int* __restrict__ sel, const int* __restrict__ bbase,
                            int* __restrict__ pos_tk, int* __restrict__ scat) {
  __shared__ int se[256];
  int i = threadIdx.x;
  int a = blockIdx.x * 256 + i;
  int e = sel[a];
  se[i] = e;
  __syncthreads();
  int r = 0;
  for (int j = 0; j < i; j++) r += (se[j] == e) ? 1 : 0;
  int pos = bbase[blockIdx.x * 16 + e] + r;
  if (pos < CAP) { pos_tk[a] = pos; scat[e * CAP + pos] = a >> 1; }
  else           { pos_tk[a] = -1; }
}

// ---------------- GEMM1: expert_in @ w_up_gate, fused SiLU*up ----------------
// tiles: M=128 (c), N=64 (i) for BOTH gate and up; BK=64; 4 waves, each wave
// 64x32 per output via 4x2 grid of 16x16x32 mfma, 2 k-substeps per tile.
// XOR-swizzled LDS (slot ^= row&7) via pre-swizzled global source (rule 21).
// Double-buffered, counted-vmcnt pipeline (T3+T4): the prefetch issued into
// the other buffer stays IN FLIGHT across both barriers; vmcnt(8) only waits
// for the tile issued one full compute-phase ago.

__global__ __launch_bounds__(256) void gemm1_kernel(
    const unsigned short* __restrict__ xb, const unsigned short* __restrict__ wtg,
    const int* __restrict__ scat, const int* __restrict__ capc,
    const unsigned short* __restrict__ zrow, unsigned short* __restrict__ act) {
  int e = blockIdx.z, ct = blockIdx.x, it = blockIdx.y;
  if (ct * 128 >= capc[e]) return;
  __shared__ __align__(16) unsigned short As0[128 * 64], As1[128 * 64];  // 16 KB each
  __shared__ __align__(16) unsigned short Bg0[64 * 64],  Bg1[64 * 64];   //  8 KB each
  __shared__ __align__(16) unsigned short Bu0[64 * 64],  Bu1[64 * 64];   //  8 KB each
  const int t = threadIdx.x, w = t >> 6, l = t & 63;
  const int lr8   = l >> 3;                  // row within 8-row staging group
  const int koffs = ((l & 7) ^ lr8) * 8;     // pre-swizzled global 16B-slot

  const unsigned short* aptr[4];
#pragma unroll
  for (int j = 0; j < 4; j++) {
    int c0 = ct * 128 + w * 32 + j * 8 + lr8;
    int tok = scat[e * CAP + c0];
    aptr[j] = (tok >= 0 ? xb + (size_t)tok * DIM : zrow) + koffs;
  }
  const unsigned short* bgp[2];
  const unsigned short* bup[2];
#pragma unroll
  for (int j = 0; j < 2; j++) {
    int n0 = it * 64 + w * 16 + j * 8 + lr8;
    bgp[j] = wtg + ((size_t)e * (2 * IDIM) + n0) * DIM + koffs;
    bup[j] = bgp[j] + (size_t)IDIM * DIM;
  }

  floatx4 accg[8], accu[8];
#pragma unroll
  for (int i = 0; i < 8; i++) {
    accg[i] = (floatx4){0.f, 0.f, 0.f, 0.f};
    accu[i] = (floatx4){0.f, 0.f, 0.f, 0.f};
  }
  const int wm = w >> 1, wn = w & 1;
  const int rl = l & 15, lq = l >> 4, sx = l & 7;

  auto stage = [&](int k0, unsigned short* As, unsigned short* Bg, unsigned short* Bu) {
#pragma unroll
    for (int j = 0; j < 4; j++)
      gld_lds16(aptr[j] + k0, (char*)As + w * 4096 + j * 1024);
#pragma unroll
    for (int j = 0; j < 2; j++) {
      gld_lds16(bgp[j] + k0, (char*)Bg + w * 2048 + j * 1024);
      gld_lds16(bup[j] + k0, (char*)Bu + w * 2048 + j * 1024);
    }
  };
  auto compute = [&](const unsigned short* As, const unsigned short* Bg,
                     const unsigned short* Bu) {
#pragma unroll
    for (int ks = 0; ks < 2; ks++) {
      const int slot = ((ks * 4 + lq) ^ sx) * 8;
      short8 af[4], bgf[2], buf2[2];
#pragma unroll
      for (int mi = 0; mi < 4; mi++)
        af[mi] = *(const short8*)(As + (wm * 64 + mi * 16 + rl) * 64 + slot);
#pragma unroll
      for (int ni = 0; ni < 2; ni++) {
        bgf[ni]  = *(const short8*)(Bg + (wn * 32 + ni * 16 + rl) * 64 + slot);
        buf2[ni] = *(const short8*)(Bu + (wn * 32 + ni * 16 + rl) * 64 + slot);
      }
#pragma unroll
      for (int mi = 0; mi < 4; mi++)
#pragma unroll
        for (int ni = 0; ni < 2; ni++) {
          accg[mi * 2 + ni] = __builtin_amdgcn_mfma_f32_16x16x32_bf16(af[mi], bgf[ni],  accg[mi * 2 + ni], 0, 0, 0);
          accu[mi * 2 + ni] = __builtin_amdgcn_mfma_f32_16x16x32_bf16(af[mi], buf2[ni], accu[mi * 2 + ni], 0, 0, 0);
        }
    }
  };

  const int NT = DIM / 64;   // 16 (even)
  stage(0, As0, Bg0, Bu0);
  int tt = 0;
  for (; tt + 2 < NT; tt += 2) {
    stage((tt + 1) * 64, As1, Bg1, Bu1);
    sbar_vm8();                       // tile tt landed everywhere
    compute(As0, Bg0, Bu0);
    sbar();                           // buf0 free to overwrite
    stage((tt + 2) * 64, As0, Bg0, Bu0);
    sbar_vm8();                       // tile tt+1 landed
    compute(As1, Bg1, Bu1);
    sbar();                           // buf1 free
  }
  // tt == NT-2: buf0 holds tile NT-2
  stage((NT - 1) * 64, As1, Bg1, Bu1);
  sbar_vm8();
  compute(As0, Bg0, Bu0);
  sbar_vm0();                         // drain last tile's loads
  compute(As1, Bg1, Bu1);

  size_t abase = ((size_t)e * CAP + (size_t)ct * 128) * IDIM + (size_t)it * 64;
#pragma unroll
  for (int mi = 0; mi < 4; mi++)
#pragma unroll
    for (int reg = 0; reg < 4; reg++) {
      int m = wm * 64 + mi * 16 + lq * 4 + reg;
#pragma unroll
      for (int ni = 0; ni < 2; ni++) {
        int n = wn * 32 + ni * 16 + (l & 15);
        float g = accg[mi * 2 + ni][reg];
        float u = accu[mi * 2 + ni][reg];
        float a = g / (1.f + __expf(-g)) * u;   // silu(g)*u
        act[abase + (size_t)m * IDIM + n] = f2bf(a);
      }
    }
}

// ---------------- GEMM2: act @ w_down ----------------
// same structure: M=128, N=64, BK=64, swizzled LDS, counted-vmcnt pipeline.

__global__ __launch_bounds__(256) void gemm2_kernel(
    const unsigned short* __restrict__ act, const unsigned short* __restrict__ wtd,
    const int* __restrict__ capc, unsigned short* __restrict__ eout) {
  int e = blockIdx.z, ct = blockIdx.x, it = blockIdx.y;
  if (ct * 128 >= capc[e]) return;
  __shared__ __align__(16) unsigned short As0[128 * 64], As1[128 * 64];  // 16 KB each
  __shared__ __align__(16) unsigned short Bs0[64 * 64],  Bs1[64 * 64];   //  8 KB each
  const int t = threadIdx.x, w = t >> 6, l = t & 63;
  const int lr8   = l >> 3;
  const int koffs = ((l & 7) ^ lr8) * 8;

  const unsigned short* aptr[4];
#pragma unroll
  for (int j = 0; j < 4; j++)
    aptr[j] = act + ((size_t)e * CAP + ct * 128 + w * 32 + j * 8 + lr8) * IDIM + koffs;
  const unsigned short* bptr[2];
#pragma unroll
  for (int j = 0; j < 2; j++)
    bptr[j] = wtd + ((size_t)e * DIM + it * 64 + w * 16 + j * 8 + lr8) * IDIM + koffs;

  floatx4 acc[8];
#pragma unroll
  for (int i = 0; i < 8; i++) acc[i] = (floatx4){0.f, 0.f, 0.f, 0.f};
  const int wm = w >> 1, wn = w & 1;
  const int rl = l & 15, lq = l >> 4, sx = l & 7;

  auto stage = [&](int k0, unsigned short* As, unsigned short* Bs) {
#pragma unroll
    for (int j = 0; j < 4; j++)
      gld_lds16(aptr[j] + k0, (char*)As + w * 4096 + j * 1024);
#pragma unroll
    for (int j = 0; j < 2; j++)
      gld_lds16(bptr[j] + k0, (char*)Bs + w * 2048 + j * 1024);
  };
  auto compute = [&](const unsigned short* As, const unsigned short* Bs) {
#pragma unroll
    for (int ks = 0; ks < 2; ks++) {
      const int slot = ((ks * 4 + lq) ^ sx) * 8;
      short8 af[4], bf2[2];
#pragma unroll
      for (int mi = 0; mi < 4; mi++)
        af[mi] = *(const short8*)(As + (wm * 64 + mi * 16 + rl) * 64 + slot);
#pragma unroll
      for (int ni = 0; ni < 2; ni++)
        bf2[ni] = *(const short8*)(Bs + (wn * 32 + ni * 16 + rl) * 64 + slot);
#pragma unroll
      for (int mi = 0; mi < 4; mi++)
#pragma unroll
        for (int ni = 0; ni < 2; ni++)
          acc[mi * 2 + ni] = __builtin_amdgcn_mfma_f32_16x16x32_bf16(af[mi], bf2[ni], acc[mi * 2 + ni], 0, 0, 0);
    }
  };

  const int NT = IDIM / 64;  // 44 (even)
  stage(0, As0, Bs0);
  int tt = 0;
  for (; tt + 2 < NT; tt += 2) {
    stage((tt + 1) * 64, As1, Bs1);
    sbar_vm6();
    compute(As0, Bs0);
    sbar();
    stage((tt + 2) * 64, As0, Bs0);
    sbar_vm6();
    compute(As1, Bs1);
    sbar();
  }
  stage((NT - 1) * 64, As1, Bs1);
  sbar_vm6();
  compute(As0, Bs0);
  sbar_vm0();
  compute(As1, Bs1);

  size_t obase = ((size_t)e * CAP + (size_t)ct * 128) * DIM + (size_t)it * 64;
#pragma unroll
  for (int mi = 0; mi < 4; mi++)
#pragma unroll
    for (int reg = 0; reg < 4; reg++) {
      int m = wm * 64 + mi * 16 + lq * 4 + reg;
#pragma unroll
      for (int ni = 0; ni < 2; ni++) {
        int n = wn * 32 + ni * 16 + (l & 15);
        eout[obase + (size_t)m * DIM + n] = f2bf(acc[mi * 2 + ni][reg]);
      }
    }
}

// ---------------- gather + weighted combine ----------------

__global__ void combine_kernel(const unsigned short* __restrict__ eout,
                               const int* __restrict__ sel, const int* __restrict__ pos_tk,
                               const float* __restrict__ wcomb, float* __restrict__ routed) {
  int tok = blockIdx.x;
  int d = threadIdx.x * 4;
  float a0 = 0.f, a1 = 0.f, a2 = 0.f, a3 = 0.f;
#pragma unroll
  for (int s = 0; s < 2; s++) {
    int a = tok * 2 + s;
    int p = pos_tk[a];
    if (p >= 0) {
      int e = sel[a];
      float wgt = wcomb[a];
      const unsigned short* row = eout + ((size_t)e * CAP + p) * DIM + d;
      ushort4 r = *(const ushort4*)row;
      a0 += wgt * bf2f(r.x); a1 += wgt * bf2f(r.y);
      a2 += wgt * bf2f(r.z); a3 += wgt * bf2f(r.w);
    }
  }
  float4 o = {a0, a1, a2, a3};
  *(float4*)(routed + (size_t)tok * DIM + d) = o;
}

__global__ void finalize_kernel(const int* __restrict__ counts_raw, const float* __restrict__ psums,
                                const float* __restrict__ z2sum, float* __restrict__ tail) {
  if (threadIdx.x != 0 || blockIdx.x != 0) return;
  float ent = 0.f, lb = 0.f;
  for (int e = 0; e < 16; e++) {
    float c = (float)counts_raw[e];
    tail[e] = c;
    float frac = c / 65536.f;
    ent -= frac * logf(frac + 1e-6f);
    lb += frac * 2.f * (psums[e] / 32768.f);
  }
  tail[16] = ent;
  tail[17] = 16.f * lb;
  tail[18] = z2sum[0] / 32768.f;
}

// ---------------- launch ----------------

extern "C" void kernel_launch(void* const* d_in, const int* in_sizes, int n_in,
                              void* d_out, int out_size, void* d_ws, size_t ws_size,
                              hipStream_t stream) {
  (void)in_sizes; (void)n_in; (void)out_size; (void)ws_size;
  const float* x         = (const float*)d_in[0];
  const float* router    = (const float*)d_in[1];
  const float* w_up_gate = (const float*)d_in[2];
  const float* w_down    = (const float*)d_in[3];
  float* out = (float*)d_out;

  char* p = (char*)d_ws;
  size_t off = 0;
  auto alc = [&](size_t n) { void* r = p + off; off += (n + 255) & ~(size_t)255; return r; };

  unsigned short* xb   = (unsigned short*)alc((size_t)T_TOK * DIM * 2);         //  64 MB
  unsigned short* wtg  = (unsigned short*)alc((size_t)NE * 2 * IDIM * DIM * 2); // 184.5 MB
  unsigned short* wtd  = (unsigned short*)alc((size_t)NE * DIM * IDIM * 2);     //  92.3 MB
  unsigned short* act  = (unsigned short*)alc((size_t)NE * CAP * IDIM * 2);     // 461.4 MB
  unsigned short* eout = (unsigned short*)alc((size_t)NE * CAP * DIM * 2);      // 167.8 MB
  float* logits = (float*)alc((size_t)T_TOK * NE * 4);
  int*   sel    = (int*)alc((size_t)TKA * 4);
  float* wcomb  = (float*)alc((size_t)TKA * 4);
  int*   pos_tk = (int*)alc((size_t)TKA * 4);
  int*   scat   = (int*)alc((size_t)NE * CAP * 4);
  int*   bhist  = (int*)alc(256 * 16 * 4);
  int*   bbase  = (int*)alc(256 * 16 * 4);
  int*   capc   = (int*)alc(64);
  int*   counts_raw = (int*)alc(64);
  float* psums  = (float*)alc(64);
  float* z2     = (float*)alc(64);
  unsigned short* zrow = (unsigned short*)alc(DIM * 2);

  hipMemsetAsync(counts_raw, 0, 64, stream);
  hipMemsetAsync(psums, 0, 64, stream);
  hipMemsetAsync(z2, 0, 64, stream);
  hipMemsetAsync(scat, 0xFF, (size_t)NE * CAP * 4, stream);
  hipMemsetAsync(zrow, 0, DIM * 2, stream);

  cvtx_kernel<<<T_TOK * DIM / (256 * 8), 256, 0, stream>>>(x, xb);
  transpose_cvt<<<dim3(2 * IDIM / 64, DIM / 64, NE), 256, 0, stream>>>(w_up_gate, wtg, DIM, 2 * IDIM);
  transpose_cvt<<<dim3(DIM / 64, IDIM / 64, NE), 256, 0, stream>>>(w_down, wtd, IDIM, DIM);

  router_kernel<<<T_TOK * NE / 256, 256, 0, stream>>>(x, router, logits);
  topk_kernel<<<T_TOK / 256, 256, 0, stream>>>(logits, sel, wcomb, psums, counts_raw, z2);
  hist_kernel<<<TKA / 256, 256, 0, stream>>>(sel, bhist);
  scan_kernel<<<1, 256, 0, stream>>>(bhist, bbase, capc);
  rank_kernel<<<TKA / 256, 256, 0, stream>>>(sel, bbase, pos_tk, scat);

  gemm1_kernel<<<dim3(CAP / 128, IDIM / 64, NE), 256, 0, stream>>>(xb, wtg, scat, capc, zrow, act);
  gemm2_kernel<<<dim3(CAP / 128, DIM / 64, NE), 256, 0, stream>>>(act, wtd, capc, eout);

  combine_kernel<<<T_TOK, 256, 0, stream>>>(eout, sel, pos_tk, wcomb, out);
  finalize_kernel<<<1, 64, 0, stream>>>(counts_raw, psums, z2, out + (size_t)T_TOK * DIM);
}